// Round 16
// baseline (201.119 us; speedup 1.0000x reference)
//
#include <hip/hip_runtime.h>
#include <hip/hip_fp16.h>
#include <math.h>
#include <stdint.h>

#define N_NODES 100000
#define N_EDGES 1600000
#define N_TOT   (N_EDGES + N_NODES)   // edges + self-loops
#define NEG_SLOPE 0.2f

#define CB     512                            // dst nodes per coarse bucket
#define CBBITS 9
#define NCB    ((N_NODES + CB - 1) / CB)      // 196 coarse buckets
#define TP     4096                           // edges per partition block
#define NPB    ((N_EDGES + TP - 1) / TP)      // 391 partition blocks
#define NB1    ((N_NODES * 8 + 255) / 256)    // 3125 node1 blocks
#define WINB   10240                          // fixed ssrc window per bucket (max load ~8950)

typedef int nt_int4 __attribute__((ext_vector_type(4)));

// ---------------- fused front: node1 + block-radix partition ------------
// Blocks [0,NB1): h1 = x@W1 (+attention dots). Blocks [NB1,..): each takes
// 4096 edges, LDS histogram over 196 coarse bins, LDS scan, LDS stage
// scatter, coalesced dump to its private pairs window + ofs row.
__global__ void __launch_bounds__(256) k_front(
        const float* __restrict__ x, const float* __restrict__ W1,
        const float* __restrict__ a_src1, const float* __restrict__ a_dst1,
        __half* __restrict__ h1h, __half* __restrict__ as1h,
        float* __restrict__ ad1,
        const int* __restrict__ src, const int* __restrict__ dst,
        int* __restrict__ ofs, unsigned* __restrict__ pairs) {
    if (blockIdx.x < NB1) {
        // ---- node1 ----
        int tid  = blockIdx.x * 256 + threadIdx.x;
        int n    = tid >> 3;
        int head = tid & 7;
        if (n >= N_NODES) return;
        float xv[5];
#pragma unroll
        for (int k = 0; k < 5; ++k) xv[k] = x[n * 5 + k];
        float hv[8];
        float as = 0.f, ad = 0.f;
#pragma unroll
        for (int j = 0; j < 8; ++j) {
            int c = head * 8 + j;
            float acc = 0.f;
#pragma unroll
            for (int k = 0; k < 5; ++k) acc += xv[k] * W1[k * 64 + c];
            hv[j] = acc;
            as += acc * a_src1[c];
            ad += acc * a_dst1[c];
        }
        __half2* hp = (__half2*)&h1h[(size_t)n * 64 + head * 8];
#pragma unroll
        for (int j = 0; j < 4; ++j)
            hp[j] = __halves2half2(__float2half(hv[2 * j]), __float2half(hv[2 * j + 1]));
        as1h[n * 8 + head] = __float2half(as);
        ad1[n * 8 + head] = ad;
    } else {
        // ---- partAB ----
        __shared__ int lcnt[256];            // 196 bins padded to 256
        __shared__ int lcur[NCB];
        __shared__ unsigned stage[TP];       // 16 KB
        int blk = blockIdx.x - NB1;
        int t = threadIdx.x;
        int base = blk * TP + t * 16;
        bool act = base < N_EDGES;           // tail block: exact multiple of 16
        int nE = min(TP, N_EDGES - blk * TP);

        lcnt[t] = 0;
        __syncthreads();

        nt_int4 s4[4], d4[4];
        if (act) {
#pragma unroll
            for (int i = 0; i < 4; ++i) {
                s4[i] = __builtin_nontemporal_load((const nt_int4*)(src + base + i * 4));
                d4[i] = __builtin_nontemporal_load((const nt_int4*)(dst + base + i * 4));
#pragma unroll
                for (int j = 0; j < 4; ++j) atomicAdd(&lcnt[d4[i][j] >> CBBITS], 1);
            }
        }
        __syncthreads();

        // exclusive scan over 256 slots (Hillis-Steele, in place)
        int v = lcnt[t];
        for (int off = 1; off < 256; off <<= 1) {
            int u = (t >= off) ? lcnt[t - off] : 0;
            __syncthreads();
            lcnt[t] += u;
            __syncthreads();
        }
        int ex = lcnt[t] - v;                // exclusive prefix
        if (t < NCB) {
            lcur[t] = ex;
            ofs[blk * (NCB + 1) + t] = ex;
        }
        if (t == 0) ofs[blk * (NCB + 1) + NCB] = nE;
        __syncthreads();

        if (act) {
#pragma unroll
            for (int i = 0; i < 4; ++i)
#pragma unroll
                for (int j = 0; j < 4; ++j) {
                    int d = d4[i][j], s = s4[i][j];
                    int bin = d >> CBBITS;
                    int idx = atomicAdd(&lcur[bin], 1);
                    stage[idx] = ((unsigned)(d & (CB - 1)) << 17) | (unsigned)s;
                }
        }
        __syncthreads();
        for (int i = t; i < nE; i += 256)
            pairs[(size_t)blk * TP + i] = stage[i];      // coalesced dump
    }
}

// ---------------- bucket-local CSR build --------------------------------
// Block per bucket B. Reads its 391 run-slices via ofs; fine histogram of
// 512 dsts + shuffle scan; self-loops synthesized (preseed 1, slot 0 = own
// id). Fixed output window B*WINB — no global prefix needed.
__global__ void __launch_bounds__(256) k_csr(
        const int* __restrict__ ofs, const unsigned* __restrict__ pairs,
        int* __restrict__ rbeg, int* __restrict__ rend, int* __restrict__ ssrc) {
    __shared__ int lcnt[CB], lofs[CB], lcur[CB];
    __shared__ int wsum[4];
    int B = blockIdx.x, t = threadIdx.x;
    int nvalid = min(CB, N_NODES - B * CB);
    int obase = B * WINB;

    lcnt[t]       = (t < nvalid) ? 1 : 0;   // self-loop pre-count
    lcnt[t + 256] = (t + 256 < nvalid) ? 1 : 0;
    lcur[t] = 1; lcur[t + 256] = 1;         // slot 0 = self-loop
    __syncthreads();

    // pass 1: fine histogram over this bucket's runs
    for (int blk = t; blk < NPB; blk += 256) {
        int o0 = ofs[blk * (NCB + 1) + B];
        int o1 = ofs[blk * (NCB + 1) + B + 1];
        const unsigned* pp = pairs + (size_t)blk * TP;
        for (int k = o0; k < o1; ++k) atomicAdd(&lcnt[pp[k] >> 17], 1);
    }
    __syncthreads();

    // exclusive scan over 512 bins, 2 bins/thread
    int a = lcnt[2 * t], bq = lcnt[2 * t + 1];
    int v = a + bq;
    int ln = t & 63, wv = t >> 6;
    int sc = v;
#pragma unroll
    for (int off = 1; off < 64; off <<= 1) {
        int u = __shfl_up(sc, off, 64);
        if (ln >= off) sc += u;
    }
    if (ln == 63) wsum[wv] = sc;
    __syncthreads();
    int wbase = 0;
#pragma unroll
    for (int i = 0; i < 4; ++i) if (i < wv) wbase += wsum[i];
    int ex = wbase + sc - v;
    lofs[2 * t] = ex;
    lofs[2 * t + 1] = ex + a;

    int gi0 = B * CB + 2 * t, gi1 = gi0 + 1;
    if (gi0 < N_NODES) {
        rbeg[gi0] = obase + ex;
        rend[gi0] = obase + ex + a;
        ssrc[obase + ex] = gi0;            // self-loop record, slot 0
    }
    if (gi1 < N_NODES) {
        rbeg[gi1] = obase + ex + a;
        rend[gi1] = obase + ex + a + bq;
        ssrc[obase + ex + a] = gi1;
    }
    __syncthreads();

    // pass 2: scatter records into CSR rows
    for (int blk = t; blk < NPB; blk += 256) {
        int o0 = ofs[blk * (NCB + 1) + B];
        int o1 = ofs[blk * (NCB + 1) + B + 1];
        const unsigned* pp = pairs + (size_t)blk * TP;
        for (int k = o0; k < o1; ++k) {
            unsigned p = pp[k];
            int dl = p >> 17;
            int idx = atomicAdd(&lcur[dl], 1);
            ssrc[obase + lofs[dl] + idx] = (int)(p & 0x1FFFF);
        }
    }
}

// ---------------- layer 1 gather + softmax + ELU + fused node2 ----------
// One wave per dst. Quarter-wave = edge (eq=lane>>4), lane covers 4
// channels via one 8B dwordx2 load. x2 unrolled (8 edges in flight).
__global__ void __launch_bounds__(256) k_gather1(
        const int* __restrict__ rbeg, const int* __restrict__ rend,
        const int* __restrict__ ssrc, const float2* __restrict__ h1q,
        const __half* __restrict__ as1h, const float* __restrict__ ad1,
        const float* __restrict__ b1, const float* __restrict__ W2,
        const float* __restrict__ a_src2, const float* __restrict__ a_dst2,
        float4* __restrict__ rec) {
    int gtid = blockIdx.x * blockDim.x + threadIdx.x;
    int d    = gtid >> 6;
    int lane = threadIdx.x & 63;
    if (d >= N_NODES) return;
    int eq   = lane >> 4;      // edge slot within quad (0..3)
    int l    = lane & 15;      // channel-quad index (channels 4l..4l+3)
    int head = l >> 1;

    int beg = rbeg[d], end = rend[d];
    float adv = ad1[d * 8 + head];
    float a0 = 0.f, a1 = 0.f, a2 = 0.f, a3 = 0.f, den = 0.f;

    int k = beg;
    for (; k + 8 <= end; k += 8) {            // 2 independent quad chains
        int sA = ssrc[k + eq];
        int sB = ssrc[k + 4 + eq];
        float eA = __half2float(as1h[sA * 8 + head]);
        float eB = __half2float(as1h[sB * 8 + head]);
        float2 rA = h1q[(size_t)sA * 16 + l];
        float2 rB = h1q[(size_t)sB * 16 + l];
        float tA = eA + adv; tA = fmaxf(tA, NEG_SLOPE * tA);
        float tB = eB + adv; tB = fmaxf(tB, NEG_SLOPE * tB);
        float wA = __expf(tA), wB = __expf(tB);
        float2 fA0 = __half22float2(*(__half2*)&rA.x);
        float2 fA1 = __half22float2(*(__half2*)&rA.y);
        float2 fB0 = __half22float2(*(__half2*)&rB.x);
        float2 fB1 = __half22float2(*(__half2*)&rB.y);
        a0 += wA * fA0.x + wB * fB0.x;
        a1 += wA * fA0.y + wB * fB0.y;
        a2 += wA * fA1.x + wB * fB1.x;
        a3 += wA * fA1.y + wB * fB1.y;
        den += wA + wB;
    }
    for (; k < end; k += 4) {                  // masked tail quads
        int ki = k + eq;
        int s = ssrc[(ki < end) ? ki : beg];
        float e = __half2float(as1h[s * 8 + head]);
        float2 r = h1q[(size_t)s * 16 + l];
        float t = e + adv; t = fmaxf(t, NEG_SLOPE * t);
        float w = (ki < end) ? __expf(t) : 0.f;
        float2 f0 = __half22float2(*(__half2*)&r.x);
        float2 f1 = __half22float2(*(__half2*)&r.y);
        a0 += w * f0.x; a1 += w * f0.y;
        a2 += w * f1.x; a3 += w * f1.y;
        den += w;
    }
    // reduce across the 4 quarter-waves
    a0 += __shfl_xor(a0, 16, 64);  a0 += __shfl_xor(a0, 32, 64);
    a1 += __shfl_xor(a1, 16, 64);  a1 += __shfl_xor(a1, 32, 64);
    a2 += __shfl_xor(a2, 16, 64);  a2 += __shfl_xor(a2, 32, 64);
    a3 += __shfl_xor(a3, 16, 64);  a3 += __shfl_xor(a3, 32, 64);
    den += __shfl_xor(den, 16, 64); den += __shfl_xor(den, 32, 64);

    float inv = 1.f / den;                     // den>0 (self-loop guarantees)
    float4 bv = ((const float4*)b1)[l];
    float v0 = a0 * inv + bv.x;
    float v1 = a1 * inv + bv.y;
    float v2 = a2 * inv + bv.z;
    float v3 = a3 * inv + bv.w;
    v0 = (v0 > 0.f) ? v0 : (__expf(v0) - 1.f); // ELU
    v1 = (v1 > 0.f) ? v1 : (__expf(v1) - 1.f);
    v2 = (v2 > 0.f) ? v2 : (__expf(v2) - 1.f);
    v3 = (v3 > 0.f) ? v3 : (__expf(v3) - 1.f);

    // fused layer-2 transform: h2 = sum_c v_c * W2[c,:]
    float4 w2a = ((const float4*)W2)[2 * l];
    float4 w2b = ((const float4*)W2)[2 * l + 1];
    float h20 = v0 * w2a.x + v1 * w2a.z + v2 * w2b.x + v3 * w2b.z;
    float h21 = v0 * w2a.y + v1 * w2a.w + v2 * w2b.y + v3 * w2b.w;
#pragma unroll
    for (int off = 8; off; off >>= 1) {
        h20 += __shfl_xor(h20, off, 16);
        h21 += __shfl_xor(h21, off, 16);
    }
    if (lane == 0) {
        float as2v = h20 * a_src2[0] + h21 * a_src2[1];
        float ad2v = h20 * a_dst2[0] + h21 * a_dst2[1];
        rec[d] = make_float4(h20, h21, as2v, ad2v);
    }
}

// ---------------- layer 2: per-dst gather + log_softmax -----------------
__global__ void k_gather2(const int* __restrict__ rbeg, const int* __restrict__ rend,
                          const int* __restrict__ ssrc, const float4* __restrict__ rec,
                          const float* __restrict__ b2, float* __restrict__ out) {
    int gtid = blockIdx.x * blockDim.x + threadIdx.x;
    int d    = gtid >> 4;
    int lane = gtid & 15;
    if (d >= N_NODES) return;

    int beg = rbeg[d], end = rend[d];
    float adv = rec[d].w;
    float n0 = 0.f, n1 = 0.f, den = 0.f;
    int k = beg + lane;
    for (; k + 16 < end; k += 32) {
        int s0 = ssrc[k], s1 = ssrc[k + 16];
        float4 r0 = rec[s0];
        float4 r1 = rec[s1];
        float t0 = r0.z + adv; t0 = fmaxf(t0, NEG_SLOPE * t0);
        float t1 = r1.z + adv; t1 = fmaxf(t1, NEG_SLOPE * t1);
        float w0 = __expf(t0), w1 = __expf(t1);
        n0 += w0 * r0.x + w1 * r1.x;
        n1 += w0 * r0.y + w1 * r1.y;
        den += w0 + w1;
    }
    if (k < end) {
        int s = ssrc[k];
        float4 r = rec[s];
        float t = r.z + adv; t = fmaxf(t, NEG_SLOPE * t);
        float w = __expf(t);
        n0 += w * r.x; n1 += w * r.y; den += w;
    }
#pragma unroll
    for (int off = 8; off; off >>= 1) {
        n0  += __shfl_xor(n0,  off, 16);
        n1  += __shfl_xor(n1,  off, 16);
        den += __shfl_xor(den, off, 16);
    }
    if (lane == 0) {
        float o0 = n0 / den + b2[0];
        float o1 = n1 / den + b2[1];
        float m  = fmaxf(o0, o1);
        float lse = m + __logf(__expf(o0 - m) + __expf(o1 - m));
        out[d * 2 + 0] = o0 - lse;
        out[d * 2 + 1] = o1 - lse;
    }
}

extern "C" void kernel_launch(void* const* d_in, const int* in_sizes, int n_in,
                              void* d_out, int out_size, void* d_ws, size_t ws_size,
                              hipStream_t stream) {
    const float* x      = (const float*)d_in[0];
    const int*   ei     = (const int*)d_in[1];     // [2, E] int32
    const float* W1     = (const float*)d_in[2];
    const float* a_src1 = (const float*)d_in[3];
    const float* a_dst1 = (const float*)d_in[4];
    const float* b1     = (const float*)d_in[5];
    const float* W2     = (const float*)d_in[6];
    const float* a_src2 = (const float*)d_in[7];
    const float* a_dst2 = (const float*)d_in[8];
    const float* b2     = (const float*)d_in[9];
    float* out = (float*)d_out;

    const int* src = ei;
    const int* dst = ei + N_EDGES;

    // ---- workspace layout (~35 MB), everything written before read:
    // no memset needed.
    int* ofs    = (int*)d_ws;                                   // NPB*(NCB+1)
    int* rbeg   = ofs + NPB * (NCB + 1);                        // N
    int* rend   = rbeg + N_NODES;                               // N
    unsigned* pairs = (unsigned*)(rend + N_NODES);              // E (6.4 MB)
    int* ssrc   = (int*)(pairs + N_EDGES);                      // NCB*WINB (8 MB)
    uintptr_t pp = ((uintptr_t)(ssrc + (size_t)NCB * WINB) + 255) & ~(uintptr_t)255;
    float4*   rec  = (float4*)pp;                               // N float4
    float*    ad1  = (float*)(rec + N_NODES);                   // N*8 fp32
    __half*   h1h  = (__half*)(ad1 + (size_t)N_NODES * 8);      // N*64 fp16
    __half*   as1h = h1h + (size_t)N_NODES * 64;                // N*8 fp16

    k_front<<<NB1 + NPB, 256, 0, stream>>>(x, W1, a_src1, a_dst1, h1h, as1h, ad1,
                                           src, dst, ofs, pairs);
    k_csr<<<NCB, 256, 0, stream>>>(ofs, pairs, rbeg, rend, ssrc);
    k_gather1<<<(N_NODES * 64 + 255) / 256, 256, 0, stream>>>(rbeg, rend, ssrc,
                                                              (const float2*)h1h,
                                                              as1h, ad1, b1, W2,
                                                              a_src2, a_dst2, rec);
    k_gather2<<<(N_NODES * 16 + 255) / 256, 256, 0, stream>>>(rbeg, rend, ssrc,
                                                              rec, b2, out);
}

// Round 17
// 198.276 us; speedup vs baseline: 1.0143x; 1.0143x over previous
//
#include <hip/hip_runtime.h>
#include <hip/hip_fp16.h>
#include <math.h>
#include <stdint.h>

#define N_NODES 100000
#define N_EDGES 1600000
#define N_TOT   (N_EDGES + N_NODES)   // edges + self-loops
#define NEG_SLOPE 0.2f

#define CB     128                            // dst nodes per bucket
#define CBBITS 7
#define NCB    ((N_NODES + CB - 1) / CB)      // 782 buckets
#define TP     4096                           // edges per partition block
#define NPB    ((N_EDGES + TP - 1) / TP)      // 391 partition blocks
#define NB1    ((N_NODES * 8 + 255) / 256)    // 3125 node1 blocks
#define WINB   2560                           // fixed ssrc window per bucket (mean load 2174)

typedef int nt_int4 __attribute__((ext_vector_type(4)));

// ---------------- fused front: node1 + block-radix partition ------------
// Blocks [0,NB1): h1 = x@W1 (+attention dots). Blocks [NB1,..): each takes
// 4096 edges, LDS histogram over 782 bins (padded 1024, 4/thread scan),
// LDS stage scatter, coalesced dump to its private pairs window + ofs row.
__global__ void __launch_bounds__(256) k_front(
        const float* __restrict__ x, const float* __restrict__ W1,
        const float* __restrict__ a_src1, const float* __restrict__ a_dst1,
        __half* __restrict__ h1h, __half* __restrict__ as1h,
        float* __restrict__ ad1,
        const int* __restrict__ src, const int* __restrict__ dst,
        int* __restrict__ ofs, unsigned* __restrict__ pairs) {
    if (blockIdx.x < NB1) {
        // ---- node1 ----
        int tid  = blockIdx.x * 256 + threadIdx.x;
        int n    = tid >> 3;
        int head = tid & 7;
        if (n >= N_NODES) return;
        float xv[5];
#pragma unroll
        for (int k = 0; k < 5; ++k) xv[k] = x[n * 5 + k];
        float hv[8];
        float as = 0.f, ad = 0.f;
#pragma unroll
        for (int j = 0; j < 8; ++j) {
            int c = head * 8 + j;
            float acc = 0.f;
#pragma unroll
            for (int k = 0; k < 5; ++k) acc += xv[k] * W1[k * 64 + c];
            hv[j] = acc;
            as += acc * a_src1[c];
            ad += acc * a_dst1[c];
        }
        __half2* hp = (__half2*)&h1h[(size_t)n * 64 + head * 8];
#pragma unroll
        for (int j = 0; j < 4; ++j)
            hp[j] = __halves2half2(__float2half(hv[2 * j]), __float2half(hv[2 * j + 1]));
        as1h[n * 8 + head] = __float2half(as);
        ad1[n * 8 + head] = ad;
    } else {
        // ---- block radix partition ----
        __shared__ int lcnt[1024];           // bins (782 used), then cursors
        __shared__ int sm[256];
        __shared__ unsigned stage[TP];       // 16 KB
        int blk = blockIdx.x - NB1;
        int t = threadIdx.x;
        int base = blk * TP + t * 16;
        bool act = base < N_EDGES;           // tail block: exact multiple of 16
        int nE = min(TP, N_EDGES - blk * TP);

#pragma unroll
        for (int i = 0; i < 4; ++i) lcnt[t * 4 + i] = 0;
        __syncthreads();

        nt_int4 s4[4], d4[4];
        if (act) {
#pragma unroll
            for (int i = 0; i < 4; ++i) {
                s4[i] = __builtin_nontemporal_load((const nt_int4*)(src + base + i * 4));
                d4[i] = __builtin_nontemporal_load((const nt_int4*)(dst + base + i * 4));
#pragma unroll
                for (int j = 0; j < 4; ++j) atomicAdd(&lcnt[d4[i][j] >> CBBITS], 1);
            }
        }
        __syncthreads();

        // exclusive scan over 1024 bins, 4/thread
        int b0 = lcnt[t * 4], b1 = lcnt[t * 4 + 1], b2 = lcnt[t * 4 + 2], b3 = lcnt[t * 4 + 3];
        int local = b0 + b1 + b2 + b3;
        sm[t] = local;
        __syncthreads();
        for (int off = 1; off < 256; off <<= 1) {
            int u = (t >= off) ? sm[t - off] : 0;
            __syncthreads();
            sm[t] += u;
            __syncthreads();
        }
        int run = sm[t] - local;
        int p0 = run, p1 = run + b0, p2 = p1 + b1, p3 = p2 + b2;
        lcnt[t * 4] = p0; lcnt[t * 4 + 1] = p1;
        lcnt[t * 4 + 2] = p2; lcnt[t * 4 + 3] = p3;
        int* orow = ofs + (size_t)blk * (NCB + 1);
        if (t * 4     <= NCB) orow[t * 4]     = p0;
        if (t * 4 + 1 <= NCB) orow[t * 4 + 1] = p1;
        if (t * 4 + 2 <= NCB) orow[t * 4 + 2] = p2;
        if (t * 4 + 3 <= NCB) orow[t * 4 + 3] = p3;
        __syncthreads();

        if (act) {
#pragma unroll
            for (int i = 0; i < 4; ++i)
#pragma unroll
                for (int j = 0; j < 4; ++j) {
                    int d = d4[i][j], s = s4[i][j];
                    int bin = d >> CBBITS;
                    int idx = atomicAdd(&lcnt[bin], 1);
                    stage[idx] = ((unsigned)(d & (CB - 1)) << 17) | (unsigned)s;
                }
        }
        __syncthreads();
        for (int i = t; i < nE; i += 256)
            pairs[(size_t)blk * TP + i] = stage[i];      // coalesced dump
    }
}

// ---------------- bucket-local CSR build (782 blocks) -------------------
// Block per bucket B (128 dsts). Reads its 391 run-slices via ofs; fine
// histogram + shuffle scan; self-loops synthesized (preseed 1, slot 0 =
// own id). Fixed output window B*WINB.
__global__ void __launch_bounds__(256) k_csr(
        const int* __restrict__ ofs, const unsigned* __restrict__ pairs,
        int* __restrict__ rbeg, int* __restrict__ rend, int* __restrict__ ssrc) {
    __shared__ int lcnt[CB], lofs[CB], lcur[CB];
    __shared__ int wsum[4];
    int B = blockIdx.x, t = threadIdx.x;
    int obase = B * WINB;

    if (t < CB) {
        lcnt[t] = (B * CB + t < N_NODES) ? 1 : 0;   // self-loop pre-count
        lcur[t] = 1;                                // slot 0 = self-loop
    }
    __syncthreads();

    // pass 1: fine histogram over this bucket's runs
    for (int blk = t; blk < NPB; blk += 256) {
        int o0 = ofs[(size_t)blk * (NCB + 1) + B];
        int o1 = ofs[(size_t)blk * (NCB + 1) + B + 1];
        const unsigned* pp = pairs + (size_t)blk * TP;
        for (int k = o0; k < o1; ++k) atomicAdd(&lcnt[pp[k] >> 17], 1);
    }
    __syncthreads();

    // exclusive scan over 128 bins (first 2 waves carry data)
    int v = (t < CB) ? lcnt[t] : 0;
    int ln = t & 63, wv = t >> 6;
    int sc = v;
#pragma unroll
    for (int off = 1; off < 64; off <<= 1) {
        int u = __shfl_up(sc, off, 64);
        if (ln >= off) sc += u;
    }
    if (ln == 63) wsum[wv] = sc;
    __syncthreads();
    int wbase = (wv == 1) ? wsum[0] : 0;
    int ex = wbase + sc - v;
    if (t < CB) {
        lofs[t] = ex;
        int gi = B * CB + t;
        if (gi < N_NODES) {
            rbeg[gi] = obase + ex;
            rend[gi] = obase + ex + v;
            ssrc[obase + ex] = gi;            // self-loop record, slot 0
        }
    }
    __syncthreads();

    // pass 2: scatter records into CSR rows
    for (int blk = t; blk < NPB; blk += 256) {
        int o0 = ofs[(size_t)blk * (NCB + 1) + B];
        int o1 = ofs[(size_t)blk * (NCB + 1) + B + 1];
        const unsigned* pp = pairs + (size_t)blk * TP;
        for (int k = o0; k < o1; ++k) {
            unsigned p = pp[k];
            int dl = p >> 17;
            int idx = atomicAdd(&lcur[dl], 1);
            ssrc[obase + lofs[dl] + idx] = (int)(p & 0x1FFFF);
        }
    }
}

// ---------------- layer 1 gather + softmax + ELU + fused node2 ----------
// One wave per dst. Quarter-wave = edge (eq=lane>>4), lane covers 4
// channels. x4 unrolled: 16 independent h1-row gathers in flight.
__global__ void __launch_bounds__(256) k_gather1(
        const int* __restrict__ rbeg, const int* __restrict__ rend,
        const int* __restrict__ ssrc, const float2* __restrict__ h1q,
        const __half* __restrict__ as1h, const float* __restrict__ ad1,
        const float* __restrict__ b1, const float* __restrict__ W2,
        const float* __restrict__ a_src2, const float* __restrict__ a_dst2,
        float4* __restrict__ rec) {
    int gtid = blockIdx.x * blockDim.x + threadIdx.x;
    int d    = gtid >> 6;
    int lane = threadIdx.x & 63;
    if (d >= N_NODES) return;
    int eq   = lane >> 4;      // edge slot within quad (0..3)
    int l    = lane & 15;      // channel-quad index (channels 4l..4l+3)
    int head = l >> 1;

    int beg = rbeg[d], end = rend[d];
    float adv = ad1[d * 8 + head];
    float a0 = 0.f, a1 = 0.f, a2 = 0.f, a3 = 0.f, den = 0.f;

    int k = beg;
    for (; k + 16 <= end; k += 16) {          // 4 independent quad chains
        int sA = ssrc[k + eq];
        int sB = ssrc[k + 4 + eq];
        int sC = ssrc[k + 8 + eq];
        int sD = ssrc[k + 12 + eq];
        float eA = __half2float(as1h[sA * 8 + head]);
        float eB = __half2float(as1h[sB * 8 + head]);
        float eC = __half2float(as1h[sC * 8 + head]);
        float eD = __half2float(as1h[sD * 8 + head]);
        float2 rA = h1q[(size_t)sA * 16 + l];
        float2 rB = h1q[(size_t)sB * 16 + l];
        float2 rC = h1q[(size_t)sC * 16 + l];
        float2 rD = h1q[(size_t)sD * 16 + l];
        float tA = eA + adv; tA = fmaxf(tA, NEG_SLOPE * tA);
        float tB = eB + adv; tB = fmaxf(tB, NEG_SLOPE * tB);
        float tC = eC + adv; tC = fmaxf(tC, NEG_SLOPE * tC);
        float tD = eD + adv; tD = fmaxf(tD, NEG_SLOPE * tD);
        float wA = __expf(tA), wB = __expf(tB), wC = __expf(tC), wD = __expf(tD);
        float2 fA0 = __half22float2(*(__half2*)&rA.x);
        float2 fA1 = __half22float2(*(__half2*)&rA.y);
        float2 fB0 = __half22float2(*(__half2*)&rB.x);
        float2 fB1 = __half22float2(*(__half2*)&rB.y);
        float2 fC0 = __half22float2(*(__half2*)&rC.x);
        float2 fC1 = __half22float2(*(__half2*)&rC.y);
        float2 fD0 = __half22float2(*(__half2*)&rD.x);
        float2 fD1 = __half22float2(*(__half2*)&rD.y);
        a0 += wA * fA0.x + wB * fB0.x + wC * fC0.x + wD * fD0.x;
        a1 += wA * fA0.y + wB * fB0.y + wC * fC0.y + wD * fD0.y;
        a2 += wA * fA1.x + wB * fB1.x + wC * fC1.x + wD * fD1.x;
        a3 += wA * fA1.y + wB * fB1.y + wC * fC1.y + wD * fD1.y;
        den += wA + wB + wC + wD;
    }
    for (; k < end; k += 4) {                  // masked tail quads
        int ki = k + eq;
        int s = ssrc[(ki < end) ? ki : beg];
        float e = __half2float(as1h[s * 8 + head]);
        float2 r = h1q[(size_t)s * 16 + l];
        float t = e + adv; t = fmaxf(t, NEG_SLOPE * t);
        float w = (ki < end) ? __expf(t) : 0.f;
        float2 f0 = __half22float2(*(__half2*)&r.x);
        float2 f1 = __half22float2(*(__half2*)&r.y);
        a0 += w * f0.x; a1 += w * f0.y;
        a2 += w * f1.x; a3 += w * f1.y;
        den += w;
    }
    // reduce across the 4 quarter-waves
    a0 += __shfl_xor(a0, 16, 64);  a0 += __shfl_xor(a0, 32, 64);
    a1 += __shfl_xor(a1, 16, 64);  a1 += __shfl_xor(a1, 32, 64);
    a2 += __shfl_xor(a2, 16, 64);  a2 += __shfl_xor(a2, 32, 64);
    a3 += __shfl_xor(a3, 16, 64);  a3 += __shfl_xor(a3, 32, 64);
    den += __shfl_xor(den, 16, 64); den += __shfl_xor(den, 32, 64);

    float inv = 1.f / den;                     // den>0 (self-loop guarantees)
    float4 bv = ((const float4*)b1)[l];
    float v0 = a0 * inv + bv.x;
    float v1 = a1 * inv + bv.y;
    float v2 = a2 * inv + bv.z;
    float v3 = a3 * inv + bv.w;
    v0 = (v0 > 0.f) ? v0 : (__expf(v0) - 1.f); // ELU
    v1 = (v1 > 0.f) ? v1 : (__expf(v1) - 1.f);
    v2 = (v2 > 0.f) ? v2 : (__expf(v2) - 1.f);
    v3 = (v3 > 0.f) ? v3 : (__expf(v3) - 1.f);

    // fused layer-2 transform: h2 = sum_c v_c * W2[c,:]
    float4 w2a = ((const float4*)W2)[2 * l];
    float4 w2b = ((const float4*)W2)[2 * l + 1];
    float h20 = v0 * w2a.x + v1 * w2a.z + v2 * w2b.x + v3 * w2b.z;
    float h21 = v0 * w2a.y + v1 * w2a.w + v2 * w2b.y + v3 * w2b.w;
#pragma unroll
    for (int off = 8; off; off >>= 1) {
        h20 += __shfl_xor(h20, off, 16);
        h21 += __shfl_xor(h21, off, 16);
    }
    if (lane == 0) {
        float as2v = h20 * a_src2[0] + h21 * a_src2[1];
        float ad2v = h20 * a_dst2[0] + h21 * a_dst2[1];
        rec[d] = make_float4(h20, h21, as2v, ad2v);
    }
}

// ---------------- layer 2: per-dst gather + log_softmax -----------------
__global__ void k_gather2(const int* __restrict__ rbeg, const int* __restrict__ rend,
                          const int* __restrict__ ssrc, const float4* __restrict__ rec,
                          const float* __restrict__ b2, float* __restrict__ out) {
    int gtid = blockIdx.x * blockDim.x + threadIdx.x;
    int d    = gtid >> 4;
    int lane = gtid & 15;
    if (d >= N_NODES) return;

    int beg = rbeg[d], end = rend[d];
    float adv = rec[d].w;
    float n0 = 0.f, n1 = 0.f, den = 0.f;
    int k = beg + lane;
    for (; k + 16 < end; k += 32) {
        int s0 = ssrc[k], s1 = ssrc[k + 16];
        float4 r0 = rec[s0];
        float4 r1 = rec[s1];
        float t0 = r0.z + adv; t0 = fmaxf(t0, NEG_SLOPE * t0);
        float t1 = r1.z + adv; t1 = fmaxf(t1, NEG_SLOPE * t1);
        float w0 = __expf(t0), w1 = __expf(t1);
        n0 += w0 * r0.x + w1 * r1.x;
        n1 += w0 * r0.y + w1 * r1.y;
        den += w0 + w1;
    }
    if (k < end) {
        int s = ssrc[k];
        float4 r = rec[s];
        float t = r.z + adv; t = fmaxf(t, NEG_SLOPE * t);
        float w = __expf(t);
        n0 += w * r.x; n1 += w * r.y; den += w;
    }
#pragma unroll
    for (int off = 8; off; off >>= 1) {
        n0  += __shfl_xor(n0,  off, 16);
        n1  += __shfl_xor(n1,  off, 16);
        den += __shfl_xor(den, off, 16);
    }
    if (lane == 0) {
        float o0 = n0 / den + b2[0];
        float o1 = n1 / den + b2[1];
        float m  = fmaxf(o0, o1);
        float lse = m + __logf(__expf(o0 - m) + __expf(o1 - m));
        out[d * 2 + 0] = o0 - lse;
        out[d * 2 + 1] = o1 - lse;
    }
}

extern "C" void kernel_launch(void* const* d_in, const int* in_sizes, int n_in,
                              void* d_out, int out_size, void* d_ws, size_t ws_size,
                              hipStream_t stream) {
    const float* x      = (const float*)d_in[0];
    const int*   ei     = (const int*)d_in[1];     // [2, E] int32
    const float* W1     = (const float*)d_in[2];
    const float* a_src1 = (const float*)d_in[3];
    const float* a_dst1 = (const float*)d_in[4];
    const float* b1     = (const float*)d_in[5];
    const float* W2     = (const float*)d_in[6];
    const float* a_src2 = (const float*)d_in[7];
    const float* a_dst2 = (const float*)d_in[8];
    const float* b2     = (const float*)d_in[9];
    float* out = (float*)d_out;

    const int* src = ei;
    const int* dst = ei + N_EDGES;

    // ---- workspace layout (~38 MB), everything written before read:
    // no memset needed.
    int* ofs    = (int*)d_ws;                                   // NPB*(NCB+1) (1.2 MB)
    int* rbeg   = ofs + (size_t)NPB * (NCB + 1);                // N
    int* rend   = rbeg + N_NODES;                               // N
    unsigned* pairs = (unsigned*)(rend + N_NODES);              // E (6.4 MB)
    int* ssrc   = (int*)(pairs + N_EDGES);                      // NCB*WINB (8 MB)
    uintptr_t pp = ((uintptr_t)(ssrc + (size_t)NCB * WINB) + 255) & ~(uintptr_t)255;
    float4*   rec  = (float4*)pp;                               // N float4
    float*    ad1  = (float*)(rec + N_NODES);                   // N*8 fp32
    __half*   h1h  = (__half*)(ad1 + (size_t)N_NODES * 8);      // N*64 fp16
    __half*   as1h = h1h + (size_t)N_NODES * 64;                // N*8 fp16

    k_front<<<NB1 + NPB, 256, 0, stream>>>(x, W1, a_src1, a_dst1, h1h, as1h, ad1,
                                           src, dst, ofs, pairs);
    k_csr<<<NCB, 256, 0, stream>>>(ofs, pairs, rbeg, rend, ssrc);
    k_gather1<<<(N_NODES * 64 + 255) / 256, 256, 0, stream>>>(rbeg, rend, ssrc,
                                                              (const float2*)h1h,
                                                              as1h, ad1, b1, W2,
                                                              a_src2, a_dst2, rec);
    k_gather2<<<(N_NODES * 16 + 255) / 256, 256, 0, stream>>>(rbeg, rend, ssrc,
                                                              rec, b2, out);
}

// Round 18
// 181.111 us; speedup vs baseline: 1.1105x; 1.0948x over previous
//
#include <hip/hip_runtime.h>
#include <hip/hip_fp16.h>
#include <math.h>
#include <stdint.h>

#define N_NODES 100000
#define N_EDGES 1600000
#define N_TOT   (N_EDGES + N_NODES)   // edges + self-loops
#define NEG_SLOPE 0.2f

#define CB     128                            // dst nodes per bucket
#define CBBITS 7
#define NCB    ((N_NODES + CB - 1) / CB)      // 782 buckets
#define TP     4096                           // edges per partition block
#define NPB    ((N_EDGES + TP - 1) / TP)      // 391 partition blocks
#define WINB   2560                           // fixed ssrc window per bucket (mean load 2174, +11 sigma)

typedef int nt_int4 __attribute__((ext_vector_type(4)));

// ---------------- layer 1: node transform -------------------------------
__global__ void k_node1(const float* __restrict__ x, const float* __restrict__ W1,
                        const float* __restrict__ a_src1, const float* __restrict__ a_dst1,
                        __half* __restrict__ h1h, __half* __restrict__ as1h,
                        float* __restrict__ ad1) {
    int tid  = blockIdx.x * blockDim.x + threadIdx.x;
    int n    = tid >> 3;
    int head = tid & 7;
    if (n >= N_NODES) return;

    float xv[5];
#pragma unroll
    for (int k = 0; k < 5; ++k) xv[k] = x[n * 5 + k];

    float hv[8];
    float as = 0.f, ad = 0.f;
#pragma unroll
    for (int j = 0; j < 8; ++j) {
        int c = head * 8 + j;
        float acc = 0.f;
#pragma unroll
        for (int k = 0; k < 5; ++k) acc += xv[k] * W1[k * 64 + c];
        hv[j] = acc;
        as += acc * a_src1[c];
        ad += acc * a_dst1[c];
    }
    __half2* hp = (__half2*)&h1h[(size_t)n * 64 + head * 8];
#pragma unroll
    for (int j = 0; j < 4; ++j)
        hp[j] = __halves2half2(__float2half(hv[2 * j]), __float2half(hv[2 * j + 1]));
    as1h[n * 8 + head] = __float2half(as);
    ad1[n * 8 + head] = ad;
}

// ---------------- block-radix partition (391 blocks) --------------------
// Each block: 4096 edges, LDS histogram over 782 bins (padded 1024,
// 4/thread scan), LDS stage scatter, coalesced dump + ofs row.
__global__ void __launch_bounds__(256) k_part(
        const int* __restrict__ src, const int* __restrict__ dst,
        int* __restrict__ ofs, unsigned* __restrict__ pairs) {
    __shared__ int lcnt[1024];           // bins (782 used), then cursors
    __shared__ int sm[256];
    __shared__ unsigned stage[TP];       // 16 KB
    int blk = blockIdx.x;
    int t = threadIdx.x;
    int base = blk * TP + t * 16;
    bool act = base < N_EDGES;           // tail block: exact multiple of 16
    int nE = min(TP, N_EDGES - blk * TP);

#pragma unroll
    for (int i = 0; i < 4; ++i) lcnt[t * 4 + i] = 0;
    __syncthreads();

    nt_int4 s4[4], d4[4];
    if (act) {
#pragma unroll
        for (int i = 0; i < 4; ++i) {
            s4[i] = __builtin_nontemporal_load((const nt_int4*)(src + base + i * 4));
            d4[i] = __builtin_nontemporal_load((const nt_int4*)(dst + base + i * 4));
#pragma unroll
            for (int j = 0; j < 4; ++j) atomicAdd(&lcnt[d4[i][j] >> CBBITS], 1);
        }
    }
    __syncthreads();

    // exclusive scan over 1024 bins, 4/thread
    int b0 = lcnt[t * 4], b1 = lcnt[t * 4 + 1], b2 = lcnt[t * 4 + 2], b3 = lcnt[t * 4 + 3];
    int local = b0 + b1 + b2 + b3;
    sm[t] = local;
    __syncthreads();
    for (int off = 1; off < 256; off <<= 1) {
        int u = (t >= off) ? sm[t - off] : 0;
        __syncthreads();
        sm[t] += u;
        __syncthreads();
    }
    int run = sm[t] - local;
    int p0 = run, p1 = run + b0, p2 = p1 + b1, p3 = p2 + b2;
    lcnt[t * 4] = p0; lcnt[t * 4 + 1] = p1;
    lcnt[t * 4 + 2] = p2; lcnt[t * 4 + 3] = p3;
    int* orow = ofs + (size_t)blk * (NCB + 1);
    if (t * 4     <= NCB) orow[t * 4]     = p0;
    if (t * 4 + 1 <= NCB) orow[t * 4 + 1] = p1;
    if (t * 4 + 2 <= NCB) orow[t * 4 + 2] = p2;
    if (t * 4 + 3 <= NCB) orow[t * 4 + 3] = p3;
    __syncthreads();

    if (act) {
#pragma unroll
        for (int i = 0; i < 4; ++i)
#pragma unroll
            for (int j = 0; j < 4; ++j) {
                int d = d4[i][j], s = s4[i][j];
                int bin = d >> CBBITS;
                int idx = atomicAdd(&lcnt[bin], 1);
                stage[idx] = ((unsigned)(d & (CB - 1)) << 17) | (unsigned)s;
            }
    }
    __syncthreads();
    for (int i = t; i < nE; i += 256)
        pairs[(size_t)blk * TP + i] = stage[i];      // coalesced dump
}

// ---------------- bucket-local CSR build, single-pass (782 blocks) ------
// Block per bucket B (128 dsts). Loads its run-slices ONCE into LDS
// (histogramming on the fly), shuffle scan, scatter into a second LDS
// buffer in final CSR order, coalesced dump to ssrc. Self-loops
// synthesized (preseed 1, slot 0 = own id).
__global__ void __launch_bounds__(256) k_csr(
        const int* __restrict__ ofs, const unsigned* __restrict__ pairs,
        int* __restrict__ rbeg, int* __restrict__ rend, int* __restrict__ ssrc) {
    __shared__ unsigned stIn[WINB];      // 10.25 KB
    __shared__ int stOut[WINB];          // 10.25 KB
    __shared__ int lcnt[CB], lofs[CB], lcur[CB];
    __shared__ int wsum[2];
    __shared__ int acur;
    int B = blockIdx.x, t = threadIdx.x;
    int nvalid = min(CB, N_NODES - B * CB);
    int obase = B * WINB;

    if (t < CB) {
        lcnt[t] = (t < nvalid) ? 1 : 0;   // self-loop pre-count
        lcur[t] = 1;                      // slot 0 = self-loop
    }
    if (t == 0) acur = 0;
    __syncthreads();

    // single pass: append records to stIn + histogram
    for (int blk = t; blk < NPB; blk += 256) {
        int o0 = ofs[(size_t)blk * (NCB + 1) + B];
        int o1 = ofs[(size_t)blk * (NCB + 1) + B + 1];
        int n = o1 - o0;
        if (n > 0) {
            int p = atomicAdd(&acur, n);
            const unsigned* pp = pairs + (size_t)blk * TP + o0;
            for (int i = 0; i < n; ++i) {
                unsigned r = pp[i];
                stIn[p + i] = r;
                atomicAdd(&lcnt[r >> 17], 1);
            }
        }
    }
    __syncthreads();
    int m = acur;

    // exclusive scan over 128 bins (first 2 waves carry data)
    int v = (t < CB) ? lcnt[t] : 0;
    int ln = t & 63, wv = t >> 6;
    int sc = v;
#pragma unroll
    for (int off = 1; off < 64; off <<= 1) {
        int u = __shfl_up(sc, off, 64);
        if (ln >= off) sc += u;
    }
    if (ln == 63 && wv < 2) wsum[wv] = sc;
    __syncthreads();
    int wbase = (wv == 1) ? wsum[0] : 0;
    int ex = wbase + sc - v;
    if (t < CB) {
        lofs[t] = ex;
        int gi = B * CB + t;
        if (gi < N_NODES) {
            rbeg[gi] = obase + ex;
            rend[gi] = obase + ex + v;
            stOut[ex] = gi;               // self-loop record, slot 0
        }
    }
    __syncthreads();

    // scatter into final CSR order (LDS -> LDS)
    for (int k = t; k < m; k += 256) {
        unsigned p = stIn[k];
        int dl = p >> 17;
        int idx = atomicAdd(&lcur[dl], 1);
        stOut[lofs[dl] + idx] = (int)(p & 0x1FFFF);
    }
    __syncthreads();

    // coalesced dump
    int tot = m + nvalid;
    for (int i = t; i < tot; i += 256) ssrc[obase + i] = stOut[i];
}

// ---------------- layer 1 gather + softmax + ELU + fused node2 ----------
// One wave per dst. Quarter-wave = edge (eq=lane>>4), lane covers 4
// channels. x4 unrolled: 16 independent h1-row gathers in flight.
__global__ void __launch_bounds__(256) k_gather1(
        const int* __restrict__ rbeg, const int* __restrict__ rend,
        const int* __restrict__ ssrc, const float2* __restrict__ h1q,
        const __half* __restrict__ as1h, const float* __restrict__ ad1,
        const float* __restrict__ b1, const float* __restrict__ W2,
        const float* __restrict__ a_src2, const float* __restrict__ a_dst2,
        float4* __restrict__ rec) {
    int gtid = blockIdx.x * blockDim.x + threadIdx.x;
    int d    = gtid >> 6;
    int lane = threadIdx.x & 63;
    if (d >= N_NODES) return;
    int eq   = lane >> 4;      // edge slot within quad (0..3)
    int l    = lane & 15;      // channel-quad index (channels 4l..4l+3)
    int head = l >> 1;

    int beg = rbeg[d], end = rend[d];
    float adv = ad1[d * 8 + head];
    float a0 = 0.f, a1 = 0.f, a2 = 0.f, a3 = 0.f, den = 0.f;

    int k = beg;
    for (; k + 16 <= end; k += 16) {          // 4 independent quad chains
        int sA = ssrc[k + eq];
        int sB = ssrc[k + 4 + eq];
        int sC = ssrc[k + 8 + eq];
        int sD = ssrc[k + 12 + eq];
        float eA = __half2float(as1h[sA * 8 + head]);
        float eB = __half2float(as1h[sB * 8 + head]);
        float eC = __half2float(as1h[sC * 8 + head]);
        float eD = __half2float(as1h[sD * 8 + head]);
        float2 rA = h1q[(size_t)sA * 16 + l];
        float2 rB = h1q[(size_t)sB * 16 + l];
        float2 rC = h1q[(size_t)sC * 16 + l];
        float2 rD = h1q[(size_t)sD * 16 + l];
        float tA = eA + adv; tA = fmaxf(tA, NEG_SLOPE * tA);
        float tB = eB + adv; tB = fmaxf(tB, NEG_SLOPE * tB);
        float tC = eC + adv; tC = fmaxf(tC, NEG_SLOPE * tC);
        float tD = eD + adv; tD = fmaxf(tD, NEG_SLOPE * tD);
        float wA = __expf(tA), wB = __expf(tB), wC = __expf(tC), wD = __expf(tD);
        float2 fA0 = __half22float2(*(__half2*)&rA.x);
        float2 fA1 = __half22float2(*(__half2*)&rA.y);
        float2 fB0 = __half22float2(*(__half2*)&rB.x);
        float2 fB1 = __half22float2(*(__half2*)&rB.y);
        float2 fC0 = __half22float2(*(__half2*)&rC.x);
        float2 fC1 = __half22float2(*(__half2*)&rC.y);
        float2 fD0 = __half22float2(*(__half2*)&rD.x);
        float2 fD1 = __half22float2(*(__half2*)&rD.y);
        a0 += wA * fA0.x + wB * fB0.x + wC * fC0.x + wD * fD0.x;
        a1 += wA * fA0.y + wB * fB0.y + wC * fC0.y + wD * fD0.y;
        a2 += wA * fA1.x + wB * fB1.x + wC * fC1.x + wD * fD1.x;
        a3 += wA * fA1.y + wB * fB1.y + wC * fC1.y + wD * fD1.y;
        den += wA + wB + wC + wD;
    }
    for (; k < end; k += 4) {                  // masked tail quads
        int ki = k + eq;
        int s = ssrc[(ki < end) ? ki : beg];
        float e = __half2float(as1h[s * 8 + head]);
        float2 r = h1q[(size_t)s * 16 + l];
        float t = e + adv; t = fmaxf(t, NEG_SLOPE * t);
        float w = (ki < end) ? __expf(t) : 0.f;
        float2 f0 = __half22float2(*(__half2*)&r.x);
        float2 f1 = __half22float2(*(__half2*)&r.y);
        a0 += w * f0.x; a1 += w * f0.y;
        a2 += w * f1.x; a3 += w * f1.y;
        den += w;
    }
    // reduce across the 4 quarter-waves
    a0 += __shfl_xor(a0, 16, 64);  a0 += __shfl_xor(a0, 32, 64);
    a1 += __shfl_xor(a1, 16, 64);  a1 += __shfl_xor(a1, 32, 64);
    a2 += __shfl_xor(a2, 16, 64);  a2 += __shfl_xor(a2, 32, 64);
    a3 += __shfl_xor(a3, 16, 64);  a3 += __shfl_xor(a3, 32, 64);
    den += __shfl_xor(den, 16, 64); den += __shfl_xor(den, 32, 64);

    float inv = 1.f / den;                     // den>0 (self-loop guarantees)
    float4 bv = ((const float4*)b1)[l];
    float v0 = a0 * inv + bv.x;
    float v1 = a1 * inv + bv.y;
    float v2 = a2 * inv + bv.z;
    float v3 = a3 * inv + bv.w;
    v0 = (v0 > 0.f) ? v0 : (__expf(v0) - 1.f); // ELU
    v1 = (v1 > 0.f) ? v1 : (__expf(v1) - 1.f);
    v2 = (v2 > 0.f) ? v2 : (__expf(v2) - 1.f);
    v3 = (v3 > 0.f) ? v3 : (__expf(v3) - 1.f);

    // fused layer-2 transform: h2 = sum_c v_c * W2[c,:]
    float4 w2a = ((const float4*)W2)[2 * l];
    float4 w2b = ((const float4*)W2)[2 * l + 1];
    float h20 = v0 * w2a.x + v1 * w2a.z + v2 * w2b.x + v3 * w2b.z;
    float h21 = v0 * w2a.y + v1 * w2a.w + v2 * w2b.y + v3 * w2b.w;
#pragma unroll
    for (int off = 8; off; off >>= 1) {
        h20 += __shfl_xor(h20, off, 16);
        h21 += __shfl_xor(h21, off, 16);
    }
    if (lane == 0) {
        float as2v = h20 * a_src2[0] + h21 * a_src2[1];
        float ad2v = h20 * a_dst2[0] + h21 * a_dst2[1];
        rec[d] = make_float4(h20, h21, as2v, ad2v);
    }
}

// ---------------- layer 2: per-dst gather + log_softmax -----------------
__global__ void k_gather2(const int* __restrict__ rbeg, const int* __restrict__ rend,
                          const int* __restrict__ ssrc, const float4* __restrict__ rec,
                          const float* __restrict__ b2, float* __restrict__ out) {
    int gtid = blockIdx.x * blockDim.x + threadIdx.x;
    int d    = gtid >> 4;
    int lane = gtid & 15;
    if (d >= N_NODES) return;

    int beg = rbeg[d], end = rend[d];
    float adv = rec[d].w;
    float n0 = 0.f, n1 = 0.f, den = 0.f;
    int k = beg + lane;
    for (; k + 16 < end; k += 32) {
        int s0 = ssrc[k], s1 = ssrc[k + 16];
        float4 r0 = rec[s0];
        float4 r1 = rec[s1];
        float t0 = r0.z + adv; t0 = fmaxf(t0, NEG_SLOPE * t0);
        float t1 = r1.z + adv; t1 = fmaxf(t1, NEG_SLOPE * t1);
        float w0 = __expf(t0), w1 = __expf(t1);
        n0 += w0 * r0.x + w1 * r1.x;
        n1 += w0 * r0.y + w1 * r1.y;
        den += w0 + w1;
    }
    if (k < end) {
        int s = ssrc[k];
        float4 r = rec[s];
        float t = r.z + adv; t = fmaxf(t, NEG_SLOPE * t);
        float w = __expf(t);
        n0 += w * r.x; n1 += w * r.y; den += w;
    }
#pragma unroll
    for (int off = 8; off; off >>= 1) {
        n0  += __shfl_xor(n0,  off, 16);
        n1  += __shfl_xor(n1,  off, 16);
        den += __shfl_xor(den, off, 16);
    }
    if (lane == 0) {
        float o0 = n0 / den + b2[0];
        float o1 = n1 / den + b2[1];
        float m  = fmaxf(o0, o1);
        float lse = m + __logf(__expf(o0 - m) + __expf(o1 - m));
        out[d * 2 + 0] = o0 - lse;
        out[d * 2 + 1] = o1 - lse;
    }
}

extern "C" void kernel_launch(void* const* d_in, const int* in_sizes, int n_in,
                              void* d_out, int out_size, void* d_ws, size_t ws_size,
                              hipStream_t stream) {
    const float* x      = (const float*)d_in[0];
    const int*   ei     = (const int*)d_in[1];     // [2, E] int32
    const float* W1     = (const float*)d_in[2];
    const float* a_src1 = (const float*)d_in[3];
    const float* a_dst1 = (const float*)d_in[4];
    const float* b1     = (const float*)d_in[5];
    const float* W2     = (const float*)d_in[6];
    const float* a_src2 = (const float*)d_in[7];
    const float* a_dst2 = (const float*)d_in[8];
    const float* b2     = (const float*)d_in[9];
    float* out = (float*)d_out;

    const int* src = ei;
    const int* dst = ei + N_EDGES;

    // ---- workspace layout (~38 MB), everything written before read:
    // no memset needed.
    int* ofs    = (int*)d_ws;                                   // NPB*(NCB+1) (1.2 MB)
    int* rbeg   = ofs + (size_t)NPB * (NCB + 1);                // N
    int* rend   = rbeg + N_NODES;                               // N
    unsigned* pairs = (unsigned*)(rend + N_NODES);              // E (6.4 MB)
    int* ssrc   = (int*)(pairs + N_EDGES);                      // NCB*WINB (8 MB)
    uintptr_t pp = ((uintptr_t)(ssrc + (size_t)NCB * WINB) + 255) & ~(uintptr_t)255;
    float4*   rec  = (float4*)pp;                               // N float4
    float*    ad1  = (float*)(rec + N_NODES);                   // N*8 fp32
    __half*   h1h  = (__half*)(ad1 + (size_t)N_NODES * 8);      // N*64 fp16
    __half*   as1h = h1h + (size_t)N_NODES * 64;                // N*8 fp16

    k_node1<<<(N_NODES * 8 + 255) / 256, 256, 0, stream>>>(x, W1, a_src1, a_dst1,
                                                           h1h, as1h, ad1);
    k_part<<<NPB, 256, 0, stream>>>(src, dst, ofs, pairs);
    k_csr<<<NCB, 256, 0, stream>>>(ofs, pairs, rbeg, rend, ssrc);
    k_gather1<<<(N_NODES * 64 + 255) / 256, 256, 0, stream>>>(rbeg, rend, ssrc,
                                                              (const float2*)h1h,
                                                              as1h, ad1, b1, W2,
                                                              a_src2, a_dst2, rec);
    k_gather2<<<(N_NODES * 16 + 255) / 256, 256, 0, stream>>>(rbeg, rend, ssrc,
                                                              rec, b2, out);
}

// Round 19
// 180.161 us; speedup vs baseline: 1.1163x; 1.0053x over previous
//
#include <hip/hip_runtime.h>
#include <hip/hip_fp16.h>
#include <math.h>
#include <stdint.h>

#define N_NODES 100000
#define N_EDGES 1600000
#define N_TOT   (N_EDGES + N_NODES)   // edges + self-loops
#define NEG_SLOPE 0.2f

#define CB     128                            // dst nodes per bucket
#define CBBITS 7
#define NCB    ((N_NODES + CB - 1) / CB)      // 782 buckets
#define TP     2048                           // edges per partition block
#define NPB    ((N_EDGES + TP - 1) / TP)      // 782 partition blocks
#define WINB   2560                           // fixed ssrc window per bucket (mean load 2174, +11 sigma)

typedef int nt_int4 __attribute__((ext_vector_type(4)));

// ---------------- layer 1: node transform -------------------------------
__global__ void k_node1(const float* __restrict__ x, const float* __restrict__ W1,
                        const float* __restrict__ a_src1, const float* __restrict__ a_dst1,
                        __half* __restrict__ h1h, __half* __restrict__ as1h,
                        float* __restrict__ ad1) {
    int tid  = blockIdx.x * blockDim.x + threadIdx.x;
    int n    = tid >> 3;
    int head = tid & 7;
    if (n >= N_NODES) return;

    float xv[5];
#pragma unroll
    for (int k = 0; k < 5; ++k) xv[k] = x[n * 5 + k];

    float hv[8];
    float as = 0.f, ad = 0.f;
#pragma unroll
    for (int j = 0; j < 8; ++j) {
        int c = head * 8 + j;
        float acc = 0.f;
#pragma unroll
        for (int k = 0; k < 5; ++k) acc += xv[k] * W1[k * 64 + c];
        hv[j] = acc;
        as += acc * a_src1[c];
        ad += acc * a_dst1[c];
    }
    __half2* hp = (__half2*)&h1h[(size_t)n * 64 + head * 8];
#pragma unroll
    for (int j = 0; j < 4; ++j)
        hp[j] = __halves2half2(__float2half(hv[2 * j]), __float2half(hv[2 * j + 1]));
    as1h[n * 8 + head] = __float2half(as);
    ad1[n * 8 + head] = ad;
}

// ---------------- block-radix partition (782 blocks x 512 thr) ----------
// 4 edges/thread: short serial chains, 24 waves/CU. LDS histogram over
// 782 bins (padded 1024, 2/thread scan), LDS stage scatter, coalesced
// dump + ofs row. Bins 782..1023 are empty so the prefix at bin NCB
// equals nE — orow[NCB] is covered by the strided prefix write.
__global__ void __launch_bounds__(512) k_part(
        const int* __restrict__ src, const int* __restrict__ dst,
        int* __restrict__ ofs, unsigned* __restrict__ pairs) {
    __shared__ int lcnt[1024];           // bins (782 used), then cursors
    __shared__ int sm[512];
    __shared__ unsigned stage[TP];       // 8 KB
    int blk = blockIdx.x;
    int t = threadIdx.x;
    int base = blk * TP + t * 4;
    bool act = base < N_EDGES;           // tail block: exact multiple of 4
    int nE = min(TP, N_EDGES - blk * TP);

    lcnt[t] = 0; lcnt[t + 512] = 0;
    __syncthreads();

    nt_int4 s4, d4;
    if (act) {
        s4 = __builtin_nontemporal_load((const nt_int4*)(src + base));
        d4 = __builtin_nontemporal_load((const nt_int4*)(dst + base));
#pragma unroll
        for (int j = 0; j < 4; ++j) atomicAdd(&lcnt[d4[j] >> CBBITS], 1);
    }
    __syncthreads();

    // exclusive scan over 1024 bins, 2/thread
    int b0 = lcnt[t * 2], b1 = lcnt[t * 2 + 1];
    int local = b0 + b1;
    sm[t] = local;
    __syncthreads();
    for (int off = 1; off < 512; off <<= 1) {
        int u = (t >= off) ? sm[t - off] : 0;
        __syncthreads();
        sm[t] += u;
        __syncthreads();
    }
    int run = sm[t] - local;
    lcnt[t * 2] = run; lcnt[t * 2 + 1] = run + b0;
    int* orow = ofs + (size_t)blk * (NCB + 1);
    if (t * 2     <= NCB) orow[t * 2]     = run;
    if (t * 2 + 1 <= NCB) orow[t * 2 + 1] = run + b0;
    __syncthreads();

    if (act) {
#pragma unroll
        for (int j = 0; j < 4; ++j) {
            int d = d4[j], s = s4[j];
            int bin = d >> CBBITS;
            int idx = atomicAdd(&lcnt[bin], 1);
            stage[idx] = ((unsigned)(d & (CB - 1)) << 17) | (unsigned)s;
        }
    }
    __syncthreads();
    for (int i = t; i < nE; i += 512)
        pairs[(size_t)blk * TP + i] = stage[i];      // coalesced dump
}

// ---------------- bucket-local CSR build, single-pass (782 x 512) -------
// Block per bucket B (128 dsts). Loads its run-slices ONCE into LDS
// (histogramming on the fly), shuffle scan, scatter into a second LDS
// buffer in final CSR order, coalesced dump to ssrc. Self-loops
// synthesized (preseed 1, slot 0 = own id).
__global__ void __launch_bounds__(512) k_csr(
        const int* __restrict__ ofs, const unsigned* __restrict__ pairs,
        int* __restrict__ rbeg, int* __restrict__ rend, int* __restrict__ ssrc) {
    __shared__ unsigned stIn[WINB];      // 10.25 KB
    __shared__ int stOut[WINB];          // 10.25 KB
    __shared__ int lcnt[CB], lofs[CB], lcur[CB];
    __shared__ int wsum[2];
    __shared__ int acur;
    int B = blockIdx.x, t = threadIdx.x;
    int nvalid = min(CB, N_NODES - B * CB);
    int obase = B * WINB;

    if (t < CB) {
        lcnt[t] = (t < nvalid) ? 1 : 0;   // self-loop pre-count
        lcur[t] = 1;                      // slot 0 = self-loop
    }
    if (t == 0) acur = 0;
    __syncthreads();

    // single pass: append records to stIn + histogram
    for (int blk = t; blk < NPB; blk += 512) {
        int o0 = ofs[(size_t)blk * (NCB + 1) + B];
        int o1 = ofs[(size_t)blk * (NCB + 1) + B + 1];
        int n = o1 - o0;
        if (n > 0) {
            int p = atomicAdd(&acur, n);
            const unsigned* pp = pairs + (size_t)blk * TP + o0;
            for (int i = 0; i < n; ++i) {
                unsigned r = pp[i];
                stIn[p + i] = r;
                atomicAdd(&lcnt[r >> 17], 1);
            }
        }
    }
    __syncthreads();
    int m = acur;

    // exclusive scan over 128 bins (first 2 waves carry data)
    int v = (t < CB) ? lcnt[t] : 0;
    int ln = t & 63, wv = t >> 6;
    int sc = v;
#pragma unroll
    for (int off = 1; off < 64; off <<= 1) {
        int u = __shfl_up(sc, off, 64);
        if (ln >= off) sc += u;
    }
    if (ln == 63 && wv < 2) wsum[wv] = sc;
    __syncthreads();
    int wbase = (wv == 1) ? wsum[0] : 0;
    int ex = wbase + sc - v;
    if (t < CB) {
        lofs[t] = ex;
        int gi = B * CB + t;
        if (gi < N_NODES) {
            rbeg[gi] = obase + ex;
            rend[gi] = obase + ex + v;
            stOut[ex] = gi;               // self-loop record, slot 0
        }
    }
    __syncthreads();

    // scatter into final CSR order (LDS -> LDS)
    for (int k = t; k < m; k += 512) {
        unsigned p = stIn[k];
        int dl = p >> 17;
        int idx = atomicAdd(&lcur[dl], 1);
        stOut[lofs[dl] + idx] = (int)(p & 0x1FFFF);
    }
    __syncthreads();

    // coalesced dump
    int tot = m + nvalid;
    for (int i = t; i < tot; i += 512) ssrc[obase + i] = stOut[i];
}

// ---------------- layer 1 gather + softmax + ELU + fused node2 ----------
// One wave per dst. Quarter-wave = edge (eq=lane>>4), lane covers 4
// channels. x4 unrolled: 16 independent h1-row gathers in flight.
__global__ void __launch_bounds__(256) k_gather1(
        const int* __restrict__ rbeg, const int* __restrict__ rend,
        const int* __restrict__ ssrc, const float2* __restrict__ h1q,
        const __half* __restrict__ as1h, const float* __restrict__ ad1,
        const float* __restrict__ b1, const float* __restrict__ W2,
        const float* __restrict__ a_src2, const float* __restrict__ a_dst2,
        float4* __restrict__ rec) {
    int gtid = blockIdx.x * blockDim.x + threadIdx.x;
    int d    = gtid >> 6;
    int lane = threadIdx.x & 63;
    if (d >= N_NODES) return;
    int eq   = lane >> 4;      // edge slot within quad (0..3)
    int l    = lane & 15;      // channel-quad index (channels 4l..4l+3)
    int head = l >> 1;

    int beg = rbeg[d], end = rend[d];
    float adv = ad1[d * 8 + head];
    float a0 = 0.f, a1 = 0.f, a2 = 0.f, a3 = 0.f, den = 0.f;

    int k = beg;
    for (; k + 16 <= end; k += 16) {          // 4 independent quad chains
        int sA = ssrc[k + eq];
        int sB = ssrc[k + 4 + eq];
        int sC = ssrc[k + 8 + eq];
        int sD = ssrc[k + 12 + eq];
        float eA = __half2float(as1h[sA * 8 + head]);
        float eB = __half2float(as1h[sB * 8 + head]);
        float eC = __half2float(as1h[sC * 8 + head]);
        float eD = __half2float(as1h[sD * 8 + head]);
        float2 rA = h1q[(size_t)sA * 16 + l];
        float2 rB = h1q[(size_t)sB * 16 + l];
        float2 rC = h1q[(size_t)sC * 16 + l];
        float2 rD = h1q[(size_t)sD * 16 + l];
        float tA = eA + adv; tA = fmaxf(tA, NEG_SLOPE * tA);
        float tB = eB + adv; tB = fmaxf(tB, NEG_SLOPE * tB);
        float tC = eC + adv; tC = fmaxf(tC, NEG_SLOPE * tC);
        float tD = eD + adv; tD = fmaxf(tD, NEG_SLOPE * tD);
        float wA = __expf(tA), wB = __expf(tB), wC = __expf(tC), wD = __expf(tD);
        float2 fA0 = __half22float2(*(__half2*)&rA.x);
        float2 fA1 = __half22float2(*(__half2*)&rA.y);
        float2 fB0 = __half22float2(*(__half2*)&rB.x);
        float2 fB1 = __half22float2(*(__half2*)&rB.y);
        float2 fC0 = __half22float2(*(__half2*)&rC.x);
        float2 fC1 = __half22float2(*(__half2*)&rC.y);
        float2 fD0 = __half22float2(*(__half2*)&rD.x);
        float2 fD1 = __half22float2(*(__half2*)&rD.y);
        a0 += wA * fA0.x + wB * fB0.x + wC * fC0.x + wD * fD0.x;
        a1 += wA * fA0.y + wB * fB0.y + wC * fC0.y + wD * fD0.y;
        a2 += wA * fA1.x + wB * fB1.x + wC * fC1.x + wD * fD1.x;
        a3 += wA * fA1.y + wB * fB1.y + wC * fC1.y + wD * fD1.y;
        den += wA + wB + wC + wD;
    }
    for (; k < end; k += 4) {                  // masked tail quads
        int ki = k + eq;
        int s = ssrc[(ki < end) ? ki : beg];
        float e = __half2float(as1h[s * 8 + head]);
        float2 r = h1q[(size_t)s * 16 + l];
        float t = e + adv; t = fmaxf(t, NEG_SLOPE * t);
        float w = (ki < end) ? __expf(t) : 0.f;
        float2 f0 = __half22float2(*(__half2*)&r.x);
        float2 f1 = __half22float2(*(__half2*)&r.y);
        a0 += w * f0.x; a1 += w * f0.y;
        a2 += w * f1.x; a3 += w * f1.y;
        den += w;
    }
    // reduce across the 4 quarter-waves
    a0 += __shfl_xor(a0, 16, 64);  a0 += __shfl_xor(a0, 32, 64);
    a1 += __shfl_xor(a1, 16, 64);  a1 += __shfl_xor(a1, 32, 64);
    a2 += __shfl_xor(a2, 16, 64);  a2 += __shfl_xor(a2, 32, 64);
    a3 += __shfl_xor(a3, 16, 64);  a3 += __shfl_xor(a3, 32, 64);
    den += __shfl_xor(den, 16, 64); den += __shfl_xor(den, 32, 64);

    float inv = 1.f / den;                     // den>0 (self-loop guarantees)
    float4 bv = ((const float4*)b1)[l];
    float v0 = a0 * inv + bv.x;
    float v1 = a1 * inv + bv.y;
    float v2 = a2 * inv + bv.z;
    float v3 = a3 * inv + bv.w;
    v0 = (v0 > 0.f) ? v0 : (__expf(v0) - 1.f); // ELU
    v1 = (v1 > 0.f) ? v1 : (__expf(v1) - 1.f);
    v2 = (v2 > 0.f) ? v2 : (__expf(v2) - 1.f);
    v3 = (v3 > 0.f) ? v3 : (__expf(v3) - 1.f);

    // fused layer-2 transform: h2 = sum_c v_c * W2[c,:]
    float4 w2a = ((const float4*)W2)[2 * l];
    float4 w2b = ((const float4*)W2)[2 * l + 1];
    float h20 = v0 * w2a.x + v1 * w2a.z + v2 * w2b.x + v3 * w2b.z;
    float h21 = v0 * w2a.y + v1 * w2a.w + v2 * w2b.y + v3 * w2b.w;
#pragma unroll
    for (int off = 8; off; off >>= 1) {
        h20 += __shfl_xor(h20, off, 16);
        h21 += __shfl_xor(h21, off, 16);
    }
    if (lane == 0) {
        float as2v = h20 * a_src2[0] + h21 * a_src2[1];
        float ad2v = h20 * a_dst2[0] + h21 * a_dst2[1];
        rec[d] = make_float4(h20, h21, as2v, ad2v);
    }
}

// ---------------- layer 2: per-dst gather + log_softmax -----------------
__global__ void k_gather2(const int* __restrict__ rbeg, const int* __restrict__ rend,
                          const int* __restrict__ ssrc, const float4* __restrict__ rec,
                          const float* __restrict__ b2, float* __restrict__ out) {
    int gtid = blockIdx.x * blockDim.x + threadIdx.x;
    int d    = gtid >> 4;
    int lane = gtid & 15;
    if (d >= N_NODES) return;

    int beg = rbeg[d], end = rend[d];
    float adv = rec[d].w;
    float n0 = 0.f, n1 = 0.f, den = 0.f;
    int k = beg + lane;
    for (; k + 16 < end; k += 32) {
        int s0 = ssrc[k], s1 = ssrc[k + 16];
        float4 r0 = rec[s0];
        float4 r1 = rec[s1];
        float t0 = r0.z + adv; t0 = fmaxf(t0, NEG_SLOPE * t0);
        float t1 = r1.z + adv; t1 = fmaxf(t1, NEG_SLOPE * t1);
        float w0 = __expf(t0), w1 = __expf(t1);
        n0 += w0 * r0.x + w1 * r1.x;
        n1 += w0 * r0.y + w1 * r1.y;
        den += w0 + w1;
    }
    if (k < end) {
        int s = ssrc[k];
        float4 r = rec[s];
        float t = r.z + adv; t = fmaxf(t, NEG_SLOPE * t);
        float w = __expf(t);
        n0 += w * r.x; n1 += w * r.y; den += w;
    }
#pragma unroll
    for (int off = 8; off; off >>= 1) {
        n0  += __shfl_xor(n0,  off, 16);
        n1  += __shfl_xor(n1,  off, 16);
        den += __shfl_xor(den, off, 16);
    }
    if (lane == 0) {
        float o0 = n0 / den + b2[0];
        float o1 = n1 / den + b2[1];
        float m  = fmaxf(o0, o1);
        float lse = m + __logf(__expf(o0 - m) + __expf(o1 - m));
        out[d * 2 + 0] = o0 - lse;
        out[d * 2 + 1] = o1 - lse;
    }
}

extern "C" void kernel_launch(void* const* d_in, const int* in_sizes, int n_in,
                              void* d_out, int out_size, void* d_ws, size_t ws_size,
                              hipStream_t stream) {
    const float* x      = (const float*)d_in[0];
    const int*   ei     = (const int*)d_in[1];     // [2, E] int32
    const float* W1     = (const float*)d_in[2];
    const float* a_src1 = (const float*)d_in[3];
    const float* a_dst1 = (const float*)d_in[4];
    const float* b1     = (const float*)d_in[5];
    const float* W2     = (const float*)d_in[6];
    const float* a_src2 = (const float*)d_in[7];
    const float* a_dst2 = (const float*)d_in[8];
    const float* b2     = (const float*)d_in[9];
    float* out = (float*)d_out;

    const int* src = ei;
    const int* dst = ei + N_EDGES;

    // ---- workspace layout (~40 MB), everything written before read:
    // no memset needed.
    int* ofs    = (int*)d_ws;                                   // NPB*(NCB+1) (2.45 MB)
    int* rbeg   = ofs + (size_t)NPB * (NCB + 1);                // N
    int* rend   = rbeg + N_NODES;                               // N
    unsigned* pairs = (unsigned*)(rend + N_NODES);              // E (6.4 MB)
    int* ssrc   = (int*)(pairs + N_EDGES);                      // NCB*WINB (8 MB)
    uintptr_t pp = ((uintptr_t)(ssrc + (size_t)NCB * WINB) + 255) & ~(uintptr_t)255;
    float4*   rec  = (float4*)pp;                               // N float4
    float*    ad1  = (float*)(rec + N_NODES);                   // N*8 fp32
    __half*   h1h  = (__half*)(ad1 + (size_t)N_NODES * 8);      // N*64 fp16
    __half*   as1h = h1h + (size_t)N_NODES * 64;                // N*8 fp16

    k_node1<<<(N_NODES * 8 + 255) / 256, 256, 0, stream>>>(x, W1, a_src1, a_dst1,
                                                           h1h, as1h, ad1);
    k_part<<<NPB, 512, 0, stream>>>(src, dst, ofs, pairs);
    k_csr<<<NCB, 512, 0, stream>>>(ofs, pairs, rbeg, rend, ssrc);
    k_gather1<<<(N_NODES * 64 + 255) / 256, 256, 0, stream>>>(rbeg, rend, ssrc,
                                                              (const float2*)h1h,
                                                              as1h, ad1, b1, W2,
                                                              a_src2, a_dst2, rec);
    k_gather2<<<(N_NODES * 16 + 255) / 256, 256, 0, stream>>>(rbeg, rend, ssrc,
                                                              rec, b2, out);
}